// Round 1
// baseline (22305.986 us; speedup 1.0000x reference)
//
#include <hip/hip_runtime.h>
#include <cstdint>

// Problem constants
#define Bsz 2048
#define Ssz 50
#define Esz 256
#define Hsz 512
#define Wsz 256
#define Lsz 50
#define Vsz 51

// JAX RNG semantics: 1 = threefry_partitionable (jax >= 0.4.36 default), 0 = original
#define JAX_THREEFRY_PARTITIONABLE 1

// ---------------- threefry2x32 (20 rounds), key words (k0,k1) ----------------
__host__ __device__ __forceinline__ void threefry2x32_hd(
    unsigned k0, unsigned k1, unsigned x0, unsigned x1,
    unsigned& o0, unsigned& o1) {
  unsigned ks2 = k0 ^ k1 ^ 0x1BD11BDAu;
  x0 += k0; x1 += k1;
#define TF_RND(r) { x0 += x1; x1 = (x1 << (r)) | (x1 >> (32 - (r))); x1 ^= x0; }
  TF_RND(13) TF_RND(15) TF_RND(26) TF_RND(6)
  x0 += k1; x1 += ks2 + 1u;
  TF_RND(17) TF_RND(29) TF_RND(16) TF_RND(24)
  x0 += ks2; x1 += k0 + 2u;
  TF_RND(13) TF_RND(15) TF_RND(26) TF_RND(6)
  x0 += k0; x1 += k1 + 3u;
  TF_RND(17) TF_RND(29) TF_RND(16) TF_RND(24)
  x0 += k1; x1 += ks2 + 4u;
  TF_RND(13) TF_RND(15) TF_RND(26) TF_RND(6)
  x0 += ks2; x1 += k0 + 5u;
#undef TF_RND
  o0 = x0; o1 = x1;
}

// ---------------- prep: Wt[k][j][g] = Whh[g*512+j][k]  (k-major pack) --------
// Loads coalesced (consecutive threads walk k); stores are the scattered side
// (16B to stride-8KB lines) — one-time cost ~3 us, irrelevant.
__global__ __launch_bounds__(256) void prep_pack(const float* __restrict__ src,
                                                 float* __restrict__ dst) {
  int idx = blockIdx.x * 256 + threadIdx.x;   // < 512*512
  int j = idx >> 9, k = idx & 511;            // consecutive threads: consecutive k
  float4 v;
  v.x = src[(size_t)(0 * 512 + j) * 512 + k];
  v.y = src[(size_t)(1 * 512 + j) * 512 + k];
  v.z = src[(size_t)(2 * 512 + j) * 512 + k];
  v.w = src[(size_t)(3 * 512 + j) * 512 + k];
  ((float4*)dst)[(size_t)k * 512 + j] = v;
}

// ---------------- prep: Wbt[k][w] = Wm[w][k]  (k-major blend weights) --------
__global__ __launch_bounds__(256) void prep_wt(const float* __restrict__ src,
                                               float* __restrict__ dst) {
  int idx = blockIdx.x * 256 + threadIdx.x;   // < 256*512
  int w = idx >> 9, k = idx & 511;            // loads coalesced along k
  dst[(size_t)k * 256 + w] = src[idx];
}

// ---------------- prep: encInP[v][j][g] = emb[v].Wih[g*512+j] + bih + bhh ----
__global__ __launch_bounds__(256) void prep_encin(
    const float* __restrict__ emb, const float* __restrict__ Wih,
    const float* __restrict__ bih, const float* __restrict__ bhh,
    float* __restrict__ encInP) {
  int wid = blockIdx.x * 4 + (threadIdx.x >> 6);
  int lane = threadIdx.x & 63;
  if (wid >= Vsz * 2048) return;
  int v = wid >> 11, col = wid & 2047;
  float4 e = ((const float4*)emb)[v * 64 + lane];
  float4 w = ((const float4*)Wih)[col * 64 + lane];
  float d = e.x * w.x + e.y * w.y + e.z * w.z + e.w * w.w;
  for (int off = 32; off; off >>= 1) d += __shfl_xor(d, off);
  if (lane == 0) {
    int g = col >> 9, j = col & 511;
    encInP[(size_t)v * 2048 + j * 4 + g] = d + bih[col] + bhh[col];
  }
}

// ---------------- prep: dbiasP[j][g] = dec_bih + dec_bhh ----------------
__global__ __launch_bounds__(256) void prep_dbias(const float* __restrict__ a,
                                                  const float* __restrict__ b,
                                                  float* __restrict__ dst) {
  int col = blockIdx.x * 256 + threadIdx.x;  // < 2048
  int g = col >> 9, j = col & 511;
  dst[j * 4 + g] = a[col] + b[col];
}

// ---------------- fused gates GEMM + LSTM cell ----------------
// C4[b][j] = sum_k hin[b][k] * Wt[k][j][0..3]; tile 64b x 32j, KT=32.
// h tile staged transposed in LDS (broadcast reads); W read straight from
// global (k-major, L1/L2-resident, coalesced 512B/wave/kk) — this keeps the
// LDS read pipe (b128 ~12cyc/CU) below the FMA floor instead of 2.3x over it.
// epilogue: gates(+encIn[tok] or dbias) -> sigmoid/tanh -> c,h
__global__ __launch_bounds__(256) void gates_step(
    const float* __restrict__ hin, const float* __restrict__ Wt,
    const float* __restrict__ addtab, const int* __restrict__ input, int tstep,
    float* __restrict__ hout, float* __restrict__ cio) {
  __shared__ float hsT[32][68];     // [kk][b], +4 pad
  const int t = threadIdx.x;
  const int tj = t & 15, tb = t >> 4;
  const int bBase = (blockIdx.x >> 4) * 64;   // 32 b-tiles
  const int jBase = (blockIdx.x & 15) * 32;   // 16 j-tiles

  float4 acc[4][2];
#pragma unroll
  for (int i = 0; i < 4; ++i)
#pragma unroll
    for (int p = 0; p < 2; ++p) acc[i][p] = make_float4(0.f, 0.f, 0.f, 0.f);

  const int lrow = t >> 3;   // 0..31
  const int lc4 = t & 7;     // 0..7
  const float4* Wp = (const float4*)Wt + (size_t)jBase + tj * 2;  // + k*512 per row

  for (int k0 = 0; k0 < Hsz; k0 += 32) {
    // stage h tile (64 rows x 32 cols), transposed into hsT[k][b]
    {
      float4 v = *((const float4*)(hin + (size_t)(bBase + lrow) * Hsz + k0) + lc4);
      hsT[lc4 * 4 + 0][lrow] = v.x; hsT[lc4 * 4 + 1][lrow] = v.y;
      hsT[lc4 * 4 + 2][lrow] = v.z; hsT[lc4 * 4 + 3][lrow] = v.w;
      float4 v2 = *((const float4*)(hin + (size_t)(bBase + lrow + 32) * Hsz + k0) + lc4);
      hsT[lc4 * 4 + 0][lrow + 32] = v2.x; hsT[lc4 * 4 + 1][lrow + 32] = v2.y;
      hsT[lc4 * 4 + 2][lrow + 32] = v2.z; hsT[lc4 * 4 + 3][lrow + 32] = v2.w;
    }
    __syncthreads();
    const float4* wrow = Wp + (size_t)k0 * 512;
#pragma unroll 8
    for (int kk = 0; kk < 32; ++kk) {
      float4 w0 = wrow[0];
      float4 w1 = wrow[1];
      wrow += 512;
      float4 hv = *(const float4*)&hsT[kk][tb * 4];
#define FMA4(A, s, Wv)                       \
  A.x = fmaf(s, Wv.x, A.x); A.y = fmaf(s, Wv.y, A.y); \
  A.z = fmaf(s, Wv.z, A.z); A.w = fmaf(s, Wv.w, A.w);
      FMA4(acc[0][0], hv.x, w0) FMA4(acc[0][1], hv.x, w1)
      FMA4(acc[1][0], hv.y, w0) FMA4(acc[1][1], hv.y, w1)
      FMA4(acc[2][0], hv.z, w0) FMA4(acc[2][1], hv.z, w1)
      FMA4(acc[3][0], hv.w, w0) FMA4(acc[3][1], hv.w, w1)
#undef FMA4
    }
    __syncthreads();
  }

#pragma unroll
  for (int i = 0; i < 4; ++i) {
    const int b = bBase + tb * 4 + i;
    const float4* arow =
        (const float4*)(input ? (addtab + (size_t)input[(size_t)b * Ssz + tstep] * 2048)
                              : addtab);
#pragma unroll
    for (int p = 0; p < 2; ++p) {
      const int j = jBase + tj * 2 + p;
      float4 a = acc[i][p];
      float4 av = arow[j];
      float gi = a.x + av.x;
      float gf = a.y + av.y;
      float gg = a.z + av.z;
      float go = a.w + av.w;
      float si = 1.0f / (1.0f + expf(-gi));
      float sf = 1.0f / (1.0f + expf(-gf));
      float sg = tanhf(gg);
      float so = 1.0f / (1.0f + expf(-go));
      size_t oo = (size_t)b * Hsz + j;
      float cn = sf * cio[oo] + si * sg;
      cio[oo] = cn;
      hout[oo] = so * tanhf(cn);
    }
  }
}

// ---------------- blend GEMM: out[b][w] = sum_k h[b][k]*Wm[w][k] ----------------
// tile 32b x 64w, KT=32; W read from global k-major (Wbt[k][w]); out row stride
// parameterized (blend1 rows / blend2)
__global__ __launch_bounds__(256) void blend_gemm(
    const float* __restrict__ hin, const float* __restrict__ Wbt,
    float* __restrict__ out, int rowStride) {
  __shared__ float hsT[32][36];   // [kk][b(32)]
  const int t = threadIdx.x;
  const int tw = t & 15, tb = t >> 4;
  const int bBase = (blockIdx.x >> 2) * 32;   // 64 b-tiles
  const int wBase = (blockIdx.x & 3) * 64;    // 4 w-tiles
  float4 acc[2];
  acc[0] = make_float4(0.f, 0.f, 0.f, 0.f);
  acc[1] = make_float4(0.f, 0.f, 0.f, 0.f);
  const int lrow = t >> 3, lc4 = t & 7;
  const float4* Wp = (const float4*)Wbt + (wBase >> 2) + tw;  // + k*64 per row
  for (int k0 = 0; k0 < Hsz; k0 += 32) {
    {
      float4 v = *((const float4*)(hin + (size_t)(bBase + lrow) * Hsz + k0) + lc4);
      hsT[lc4 * 4 + 0][lrow] = v.x; hsT[lc4 * 4 + 1][lrow] = v.y;
      hsT[lc4 * 4 + 2][lrow] = v.z; hsT[lc4 * 4 + 3][lrow] = v.w;
    }
    __syncthreads();
    const float4* wrow = Wp + (size_t)k0 * 64;
#pragma unroll 8
    for (int kk = 0; kk < 32; ++kk) {
      float4 wv = wrow[0];
      wrow += 64;
      float2 hv = *(const float2*)&hsT[kk][tb * 2];
      acc[0].x = fmaf(hv.x, wv.x, acc[0].x); acc[0].y = fmaf(hv.x, wv.y, acc[0].y);
      acc[0].z = fmaf(hv.x, wv.z, acc[0].z); acc[0].w = fmaf(hv.x, wv.w, acc[0].w);
      acc[1].x = fmaf(hv.y, wv.x, acc[1].x); acc[1].y = fmaf(hv.y, wv.y, acc[1].y);
      acc[1].z = fmaf(hv.y, wv.z, acc[1].z); acc[1].w = fmaf(hv.y, wv.w, acc[1].w);
    }
    __syncthreads();
  }
#pragma unroll
  for (int i = 0; i < 2; ++i) {
    const int b = bBase + tb * 2 + i;
    *((float4*)(out + (size_t)b * rowStride + wBase) + tw) = acc[i];
  }
}

// ---------------- scores + log_softmax + gumbel sample + mask ----------------
__global__ __launch_bounds__(256) void scores_sample(
    const float* __restrict__ b1, const float* __restrict__ b2,
    const float* __restrict__ vt, unsigned long long* __restrict__ mask,
    float* __restrict__ probs, float* __restrict__ tour,
    int stepk, unsigned kA, unsigned kB) {
  __shared__ float b2s[256];
  __shared__ float vts[256];
  __shared__ float sc[52];
  const int t = threadIdx.x, b = blockIdx.x;
  b2s[t] = b2[(size_t)b * Wsz + t];
  vts[t] = vt[t];
  __syncthreads();
  const int wave = t >> 6, lane = t & 63;
  for (int s = wave; s < Ssz; s += 4) {
    const float* row = b1 + ((size_t)b * Ssz + s) * Wsz;
    float v = 0.f;
#pragma unroll
    for (int q = 0; q < 4; ++q) {
      int w = lane + 64 * q;
      v += vts[w] * tanhf(row[w] + b2s[w]);
    }
    for (int off = 32; off; off >>= 1) v += __shfl_xor(v, off);
    if (lane == 0) sc[s] = v;
  }
  __syncthreads();
  if (wave == 0) {
    unsigned long long m = mask[b];
    float x = (lane < Ssz) ? sc[lane] : -INFINITY;
    if (lane < Ssz && ((m >> lane) & 1ull)) x = -100000.0f;
    float mv = x;
    for (int off = 32; off; off >>= 1) mv = fmaxf(mv, __shfl_xor(mv, off));
    float sh = x - mv;
    float e = (lane < Ssz) ? expf(sh) : 0.f;
    float ssum = e;
    for (int off = 32; off; off >>= 1) ssum += __shfl_xor(ssum, off);
    float lg = logf(ssum);
    float logp = sh - lg;
    if (lane < Ssz) probs[(size_t)b * (Lsz * Ssz) + stepk * Ssz + lane] = logp;

    float val = -INFINITY;
    if (lane < Ssz) {
      unsigned j = (unsigned)(b * Ssz + lane);
      unsigned o0, o1, bits;
#if JAX_THREEFRY_PARTITIONABLE
      threefry2x32_hd(kA, kB, 0u, j, o0, o1);
      bits = o0 ^ o1;
#else
      if (j < 51200u) { threefry2x32_hd(kA, kB, j, j + 51200u, o0, o1); bits = o0; }
      else           { threefry2x32_hd(kA, kB, j - 51200u, j, o0, o1); bits = o1; }
#endif
      float f = __uint_as_float((bits >> 9) | 0x3F800000u) - 1.0f;
      float u = fmaxf(1.17549435e-38f, f + 1.17549435e-38f);
      val = logp - logf(-logf(u));
    }
    int idx = lane;
    for (int off = 32; off; off >>= 1) {
      float ov = __shfl_xor(val, off);
      int oi = __shfl_xor(idx, off);
      if (ov > val || (ov == val && oi < idx)) { val = ov; idx = oi; }
    }
    if (lane == 0) {
      tour[(size_t)b * Lsz + stepk] = (float)idx;
      mask[b] = m | (1ull << idx);
    }
  }
}

extern "C" void kernel_launch(void* const* d_in, const int* in_sizes, int n_in,
                              void* d_out, int out_size, void* d_ws, size_t ws_size,
                              hipStream_t stream) {
  (void)in_sizes; (void)n_in; (void)out_size; (void)ws_size;
  const int*   input = (const int*)d_in[0];
  const float* emb   = (const float*)d_in[1];
  const float* eWih  = (const float*)d_in[2];
  const float* eWhh  = (const float*)d_in[3];
  const float* ebih  = (const float*)d_in[4];
  const float* ebhh  = (const float*)d_in[5];
  /* d_in[6] dec_Wih unused: decoder input is always zero */
  const float* dWhh  = (const float*)d_in[7];
  const float* dbih  = (const float*)d_in[8];
  const float* dbhh  = (const float*)d_in[9];
  const float* W1    = (const float*)d_in[10];
  const float* W2    = (const float*)d_in[11];
  const float* vt    = (const float*)d_in[12];
  float* outF = (float*)d_out;

  float* wsf = (float*)d_ws;
  size_t o = 0;
  float* WpackE = wsf + o; o += (size_t)512 * 512 * 4;
  float* WpackD = wsf + o; o += (size_t)512 * 512 * 4;
  float* encInP = wsf + o; o += (size_t)Vsz * 2048;
  float* dbiasP = wsf + o; o += 2048;
  float* hA  = wsf + o; o += (size_t)Bsz * Hsz;
  float* hB  = wsf + o; o += (size_t)Bsz * Hsz;
  float* cE  = wsf + o; o += (size_t)Bsz * Hsz;
  float* hdA = wsf + o; o += (size_t)Bsz * Hsz;
  float* hdB = wsf + o; o += (size_t)Bsz * Hsz;
  float* cD  = wsf + o; o += (size_t)Bsz * Hsz;
  float* b2  = wsf + o; o += (size_t)Bsz * Wsz;
  float* b1  = wsf + o; o += (size_t)Bsz * Ssz * Wsz;
  unsigned long long* maskp = (unsigned long long*)(wsf + o); o += Bsz * 2;
  float* W1t = wsf + o; o += (size_t)512 * 256;
  float* W2t = wsf + o; o += (size_t)512 * 256;

  hipMemsetAsync(hA, 0, (size_t)Bsz * Hsz * 4, stream);
  hipMemsetAsync(cE, 0, (size_t)Bsz * Hsz * 4, stream);
  hipMemsetAsync(hdA, 0, (size_t)Bsz * Hsz * 4, stream);
  hipMemsetAsync(maskp, 0, (size_t)Bsz * 8, stream);

  prep_pack<<<1024, 256, 0, stream>>>(eWhh, WpackE);
  prep_pack<<<1024, 256, 0, stream>>>(dWhh, WpackD);
  prep_wt<<<512, 256, 0, stream>>>(W1, W1t);
  prep_wt<<<512, 256, 0, stream>>>(W2, W2t);
  prep_encin<<<(Vsz * 2048) / 4, 256, 0, stream>>>(emb, eWih, ebih, ebhh, encInP);
  prep_dbias<<<8, 256, 0, stream>>>(dbih, dbhh, dbiasP);

  // host-side: step keys = jax.random.split(jax.random.key(42), 50)
  unsigned kAh[Lsz], kBh[Lsz];
  for (int k = 0; k < Lsz; ++k) {
#if JAX_THREEFRY_PARTITIONABLE
    threefry2x32_hd(0u, 42u, 0u, (unsigned)k, kAh[k], kBh[k]);
#else
    unsigned a0, a1, c0, c1;
    if (k < 25) {
      threefry2x32_hd(0u, 42u, 2u * k,      2u * k + 50u, a0, a1); kAh[k] = a0;
      threefry2x32_hd(0u, 42u, 2u * k + 1u, 2u * k + 51u, c0, c1); kBh[k] = c0;
    } else {
      threefry2x32_hd(0u, 42u, 2u * k - 50u, 2u * k,      a0, a1); kAh[k] = a1;
      threefry2x32_hd(0u, 42u, 2u * k - 49u, 2u * k + 1u, c0, c1); kBh[k] = c1;
    }
#endif
  }

  // encoder
  float* hr = hA; float* hw = hB;
  for (int t = 0; t < Ssz; ++t) {
    gates_step<<<512, 256, 0, stream>>>(hr, WpackE, encInP, input, t, hw, cE);
    blend_gemm<<<256, 256, 0, stream>>>(hw, W1t, b1 + (size_t)t * Wsz, Ssz * Wsz);
    float* tp = hr; hr = hw; hw = tp;
  }
  // decoder init: c0 = last encoder h, h0 = 0 (hdA), mask = 0
  hipMemcpyAsync(cD, hr, (size_t)Bsz * Hsz * 4, hipMemcpyDeviceToDevice, stream);

  float* dr = hdA; float* dw = hdB;
  for (int k = 0; k < Lsz; ++k) {
    gates_step<<<512, 256, 0, stream>>>(dr, WpackD, dbiasP, nullptr, 0, dw, cD);
    blend_gemm<<<256, 256, 0, stream>>>(dw, W2t, b2, Wsz);
    scores_sample<<<Bsz, 256, 0, stream>>>(b1, b2, vt, maskp, outF,
                                           outF + (size_t)Bsz * Lsz * Ssz,
                                           k, kAh[k], kBh[k]);
    float* tp = dr; dr = dw; dw = tp;
  }
}

// Round 2
// 12644.183 us; speedup vs baseline: 1.7641x; 1.7641x over previous
//
#include <hip/hip_runtime.h>
#include <cstdint>

// Problem constants
#define Bsz 2048
#define Ssz 50
#define Esz 256
#define Hsz 512
#define Wsz 256
#define Lsz 50
#define Vsz 51

// JAX RNG semantics: 1 = threefry_partitionable (jax >= 0.4.36 default), 0 = original
#define JAX_THREEFRY_PARTITIONABLE 1

// ---------------- threefry2x32 (20 rounds), key words (k0,k1) ----------------
__host__ __device__ __forceinline__ void threefry2x32_hd(
    unsigned k0, unsigned k1, unsigned x0, unsigned x1,
    unsigned& o0, unsigned& o1) {
  unsigned ks2 = k0 ^ k1 ^ 0x1BD11BDAu;
  x0 += k0; x1 += k1;
#define TF_RND(r) { x0 += x1; x1 = (x1 << (r)) | (x1 >> (32 - (r))); x1 ^= x0; }
  TF_RND(13) TF_RND(15) TF_RND(26) TF_RND(6)
  x0 += k1; x1 += ks2 + 1u;
  TF_RND(17) TF_RND(29) TF_RND(16) TF_RND(24)
  x0 += ks2; x1 += k0 + 2u;
  TF_RND(13) TF_RND(15) TF_RND(26) TF_RND(6)
  x0 += k0; x1 += k1 + 3u;
  TF_RND(17) TF_RND(29) TF_RND(16) TF_RND(24)
  x0 += k1; x1 += ks2 + 4u;
  TF_RND(13) TF_RND(15) TF_RND(26) TF_RND(6)
  x0 += ks2; x1 += k0 + 5u;
#undef TF_RND
  o0 = x0; o1 = x1;
}

// ---- prep: gates W pack, scalar-stream layout ----
// Wg float layout: [jblk 0..127][k 0..511][jj 0..3][g 0..3]
//   value = Whh[g*512 + (jblk*4+jj)][k]
// Per (jblk,k): 16 contiguous floats (64B) -> one s_load_dwordx16 per kk.
__global__ __launch_bounds__(256) void prep_gpack(const float* __restrict__ src,
                                                  float* __restrict__ dst) {
  int o = blockIdx.x * 256 + threadIdx.x;   // < 512*512*4 = 1M
  int g = o & 3;
  int jj = (o >> 2) & 3;
  int k = (o >> 4) & 511;
  int jblk = o >> 13;
  int j = jblk * 4 + jj;
  dst[o] = src[(size_t)(g * 512 + j) * 512 + k];
}

// ---- prep: blend W pack: Wb float layout [wblk 0..63][k 0..511][ww 0..3] ----
//   value = Wm[(wblk*4+ww)][k]; per (wblk,k): 16B contiguous -> s_load_dwordx4.
__global__ __launch_bounds__(256) void prep_bpack(const float* __restrict__ src,
                                                  float* __restrict__ dst) {
  int o = blockIdx.x * 256 + threadIdx.x;   // < 256*512 = 131072
  int ww = o & 3;
  int k = (o >> 2) & 511;
  int wblk = o >> 11;
  dst[o] = src[(size_t)(wblk * 4 + ww) * 512 + k];
}

// ---------------- prep: encInP[v][j][g] = emb[v].Wih[g*512+j] + bih + bhh ----
__global__ __launch_bounds__(256) void prep_encin(
    const float* __restrict__ emb, const float* __restrict__ Wih,
    const float* __restrict__ bih, const float* __restrict__ bhh,
    float* __restrict__ encInP) {
  int wid = blockIdx.x * 4 + (threadIdx.x >> 6);
  int lane = threadIdx.x & 63;
  if (wid >= Vsz * 2048) return;
  int v = wid >> 11, col = wid & 2047;
  float4 e = ((const float4*)emb)[v * 64 + lane];
  float4 w = ((const float4*)Wih)[col * 64 + lane];
  float d = e.x * w.x + e.y * w.y + e.z * w.z + e.w * w.w;
  for (int off = 32; off; off >>= 1) d += __shfl_xor(d, off);
  if (lane == 0) {
    int g = col >> 9, j = col & 511;
    encInP[(size_t)v * 2048 + j * 4 + g] = d + bih[col] + bhh[col];
  }
}

// ---------------- prep: dbiasP[j][g] = dec_bih + dec_bhh ----------------
__global__ __launch_bounds__(256) void prep_dbias(const float* __restrict__ a,
                                                  const float* __restrict__ b,
                                                  float* __restrict__ dst) {
  int col = blockIdx.x * 256 + threadIdx.x;  // < 2048
  int g = col >> 9, j = col & 511;
  dst[j * 4 + g] = a[col] + b[col];
}

// ---------------- fused gates GEMM + LSTM cell (LDS-free, scalar-W) ---------
// Thread = one batch row b; block = 256 b x 4 j; grid = 8 x 128 = 1024 blocks.
// h: thread reads its OWN row from global (64B line per 16-k chunk, L1-hit).
// W: block-uniform address -> compiler emits s_load (one copy per wave via
//    SGPRs) -- bypasses the per-lane return-bandwidth wall that made both the
//    LDS-staged (r0) and vector-global (r1) variants ~2.3x over the FMA floor.
// No __shared__, no __syncthreads, no bank conflicts. 16 waves/CU.
__global__ __launch_bounds__(256) void gates_step(
    const float* __restrict__ hin, const float* __restrict__ Wg,
    const float* __restrict__ addtab, const int* __restrict__ input, int tstep,
    float* __restrict__ hout, float* __restrict__ cio) {
  const int t = threadIdx.x;
  const int jblk = blockIdx.x & 127;            // 128 j-blocks of 4 j
  const int b = (blockIdx.x >> 7) * 256 + t;    // 8 b-tiles of 256
  const float* hrow = hin + (size_t)b * Hsz;
  const float4* wp = (const float4*)Wg + (size_t)jblk * (Hsz * 4);

  // epilogue add-row pointer (hoisted; load latency overlaps the k-loop)
  const float4* arow =
      input ? (const float4*)(addtab + (size_t)input[(size_t)b * Ssz + tstep] * 2048)
            : (const float4*)addtab;

  float4 a0 = make_float4(0.f, 0.f, 0.f, 0.f);
  float4 a1 = a0, a2 = a0, a3 = a0;

#define KSTEP(HS, KI)                                              \
  {                                                                \
    const float4* wk = wp + (size_t)(k0 + (KI)) * 4;               \
    float4 w0 = wk[0], w1 = wk[1], w2 = wk[2], w3 = wk[3];         \
    float hs = (HS);                                               \
    a0.x = fmaf(hs, w0.x, a0.x); a0.y = fmaf(hs, w0.y, a0.y);      \
    a0.z = fmaf(hs, w0.z, a0.z); a0.w = fmaf(hs, w0.w, a0.w);      \
    a1.x = fmaf(hs, w1.x, a1.x); a1.y = fmaf(hs, w1.y, a1.y);      \
    a1.z = fmaf(hs, w1.z, a1.z); a1.w = fmaf(hs, w1.w, a1.w);      \
    a2.x = fmaf(hs, w2.x, a2.x); a2.y = fmaf(hs, w2.y, a2.y);      \
    a2.z = fmaf(hs, w2.z, a2.z); a2.w = fmaf(hs, w2.w, a2.w);      \
    a3.x = fmaf(hs, w3.x, a3.x); a3.y = fmaf(hs, w3.y, a3.y);      \
    a3.z = fmaf(hs, w3.z, a3.z); a3.w = fmaf(hs, w3.w, a3.w);      \
  }

  for (int k0 = 0; k0 < Hsz; k0 += 16) {
    const float4* hp = (const float4*)(hrow + k0);
    float4 h0 = hp[0], h1 = hp[1], h2 = hp[2], h3 = hp[3];
    KSTEP(h0.x, 0)  KSTEP(h0.y, 1)  KSTEP(h0.z, 2)  KSTEP(h0.w, 3)
    KSTEP(h1.x, 4)  KSTEP(h1.y, 5)  KSTEP(h1.z, 6)  KSTEP(h1.w, 7)
    KSTEP(h2.x, 8)  KSTEP(h2.y, 9)  KSTEP(h2.z, 10) KSTEP(h2.w, 11)
    KSTEP(h3.x, 12) KSTEP(h3.y, 13) KSTEP(h3.z, 14) KSTEP(h3.w, 15)
  }
#undef KSTEP

  // epilogue: 4 j's for this thread's b
  const int j0 = jblk * 4;
  float4 av0 = arow[j0], av1 = arow[j0 + 1], av2 = arow[j0 + 2], av3 = arow[j0 + 3];
  float4 cv = *(const float4*)(cio + (size_t)b * Hsz + j0);
  float4 cn, hn;

#define GATE(A, AV, CIN, COUT, HOUT)                 \
  {                                                  \
    float gi = (A).x + (AV).x;                       \
    float gf = (A).y + (AV).y;                       \
    float gg = (A).z + (AV).z;                       \
    float go = (A).w + (AV).w;                       \
    float si = 1.0f / (1.0f + expf(-gi));            \
    float sf = 1.0f / (1.0f + expf(-gf));            \
    float sg = tanhf(gg);                            \
    float so = 1.0f / (1.0f + expf(-go));            \
    float c2 = sf * (CIN) + si * sg;                 \
    (COUT) = c2;                                     \
    (HOUT) = so * tanhf(c2);                         \
  }
  GATE(a0, av0, cv.x, cn.x, hn.x)
  GATE(a1, av1, cv.y, cn.y, hn.y)
  GATE(a2, av2, cv.z, cn.z, hn.z)
  GATE(a3, av3, cv.w, cn.w, hn.w)
#undef GATE

  *(float4*)(cio + (size_t)b * Hsz + j0) = cn;
  *(float4*)(hout + (size_t)b * Hsz + j0) = hn;
}

// ---------------- blend GEMM: out[b][w] = sum_k h[b][k]*Wm[w][k] -------------
// Same LDS-free scalar-W structure. Thread = one b, 4 w's; grid = 8 x 64.
__global__ __launch_bounds__(256) void blend_gemm(
    const float* __restrict__ hin, const float* __restrict__ Wb,
    float* __restrict__ out, int rowStride) {
  const int t = threadIdx.x;
  const int wblk = blockIdx.x & 63;             // 64 w-blocks of 4 w
  const int b = (blockIdx.x >> 6) * 256 + t;    // 8 b-tiles of 256
  const float* hrow = hin + (size_t)b * Hsz;
  const float4* wp = (const float4*)Wb + (size_t)wblk * Hsz;

  float4 acc = make_float4(0.f, 0.f, 0.f, 0.f);

#define BSTEP(HS, KI)                                          \
  {                                                            \
    float4 w = wp[k0 + (KI)];                                  \
    float hs = (HS);                                           \
    acc.x = fmaf(hs, w.x, acc.x); acc.y = fmaf(hs, w.y, acc.y);\
    acc.z = fmaf(hs, w.z, acc.z); acc.w = fmaf(hs, w.w, acc.w);\
  }

  for (int k0 = 0; k0 < Hsz; k0 += 16) {
    const float4* hp = (const float4*)(hrow + k0);
    float4 h0 = hp[0], h1 = hp[1], h2 = hp[2], h3 = hp[3];
    BSTEP(h0.x, 0)  BSTEP(h0.y, 1)  BSTEP(h0.z, 2)  BSTEP(h0.w, 3)
    BSTEP(h1.x, 4)  BSTEP(h1.y, 5)  BSTEP(h1.z, 6)  BSTEP(h1.w, 7)
    BSTEP(h2.x, 8)  BSTEP(h2.y, 9)  BSTEP(h2.z, 10) BSTEP(h2.w, 11)
    BSTEP(h3.x, 12) BSTEP(h3.y, 13) BSTEP(h3.z, 14) BSTEP(h3.w, 15)
  }
#undef BSTEP

  *(float4*)(out + (size_t)b * rowStride + wblk * 4) = acc;
}

// ---------------- scores + log_softmax + gumbel sample + mask ----------------
__global__ __launch_bounds__(256) void scores_sample(
    const float* __restrict__ b1, const float* __restrict__ b2,
    const float* __restrict__ vt, unsigned long long* __restrict__ mask,
    float* __restrict__ probs, float* __restrict__ tour,
    int stepk, unsigned kA, unsigned kB) {
  __shared__ float b2s[256];
  __shared__ float vts[256];
  __shared__ float sc[52];
  const int t = threadIdx.x, b = blockIdx.x;
  b2s[t] = b2[(size_t)b * Wsz + t];
  vts[t] = vt[t];
  __syncthreads();
  const int wave = t >> 6, lane = t & 63;
  for (int s = wave; s < Ssz; s += 4) {
    const float* row = b1 + ((size_t)b * Ssz + s) * Wsz;
    float v = 0.f;
#pragma unroll
    for (int q = 0; q < 4; ++q) {
      int w = lane + 64 * q;
      v += vts[w] * tanhf(row[w] + b2s[w]);
    }
    for (int off = 32; off; off >>= 1) v += __shfl_xor(v, off);
    if (lane == 0) sc[s] = v;
  }
  __syncthreads();
  if (wave == 0) {
    unsigned long long m = mask[b];
    float x = (lane < Ssz) ? sc[lane] : -INFINITY;
    if (lane < Ssz && ((m >> lane) & 1ull)) x = -100000.0f;
    float mv = x;
    for (int off = 32; off; off >>= 1) mv = fmaxf(mv, __shfl_xor(mv, off));
    float sh = x - mv;
    float e = (lane < Ssz) ? expf(sh) : 0.f;
    float ssum = e;
    for (int off = 32; off; off >>= 1) ssum += __shfl_xor(ssum, off);
    float lg = logf(ssum);
    float logp = sh - lg;
    if (lane < Ssz) probs[(size_t)b * (Lsz * Ssz) + stepk * Ssz + lane] = logp;

    float val = -INFINITY;
    if (lane < Ssz) {
      unsigned j = (unsigned)(b * Ssz + lane);
      unsigned o0, o1, bits;
#if JAX_THREEFRY_PARTITIONABLE
      threefry2x32_hd(kA, kB, 0u, j, o0, o1);
      bits = o0 ^ o1;
#else
      if (j < 51200u) { threefry2x32_hd(kA, kB, j, j + 51200u, o0, o1); bits = o0; }
      else           { threefry2x32_hd(kA, kB, j - 51200u, j, o0, o1); bits = o1; }
#endif
      float f = __uint_as_float((bits >> 9) | 0x3F800000u) - 1.0f;
      float u = fmaxf(1.17549435e-38f, f + 1.17549435e-38f);
      val = logp - logf(-logf(u));
    }
    int idx = lane;
    for (int off = 32; off; off >>= 1) {
      float ov = __shfl_xor(val, off);
      int oi = __shfl_xor(idx, off);
      if (ov > val || (ov == val && oi < idx)) { val = ov; idx = oi; }
    }
    if (lane == 0) {
      tour[(size_t)b * Lsz + stepk] = (float)idx;
      mask[b] = m | (1ull << idx);
    }
  }
}

extern "C" void kernel_launch(void* const* d_in, const int* in_sizes, int n_in,
                              void* d_out, int out_size, void* d_ws, size_t ws_size,
                              hipStream_t stream) {
  (void)in_sizes; (void)n_in; (void)out_size; (void)ws_size;
  const int*   input = (const int*)d_in[0];
  const float* emb   = (const float*)d_in[1];
  const float* eWih  = (const float*)d_in[2];
  const float* eWhh  = (const float*)d_in[3];
  const float* ebih  = (const float*)d_in[4];
  const float* ebhh  = (const float*)d_in[5];
  /* d_in[6] dec_Wih unused: decoder input is always zero */
  const float* dWhh  = (const float*)d_in[7];
  const float* dbih  = (const float*)d_in[8];
  const float* dbhh  = (const float*)d_in[9];
  const float* W1    = (const float*)d_in[10];
  const float* W2    = (const float*)d_in[11];
  const float* vt    = (const float*)d_in[12];
  float* outF = (float*)d_out;

  float* wsf = (float*)d_ws;
  size_t o = 0;
  float* WgE  = wsf + o; o += (size_t)512 * 512 * 4;   // enc gates W pack
  float* WgD  = wsf + o; o += (size_t)512 * 512 * 4;   // dec gates W pack
  float* Wb1  = wsf + o; o += (size_t)64 * 512 * 4;    // W1 blend pack
  float* Wb2  = wsf + o; o += (size_t)64 * 512 * 4;    // W2 blend pack
  float* encInP = wsf + o; o += (size_t)Vsz * 2048;
  float* dbiasP = wsf + o; o += 2048;
  float* hA  = wsf + o; o += (size_t)Bsz * Hsz;
  float* hB  = wsf + o; o += (size_t)Bsz * Hsz;
  float* cE  = wsf + o; o += (size_t)Bsz * Hsz;
  float* hdA = wsf + o; o += (size_t)Bsz * Hsz;
  float* hdB = wsf + o; o += (size_t)Bsz * Hsz;
  float* b2  = wsf + o; o += (size_t)Bsz * Wsz;
  float* b1  = wsf + o; o += (size_t)Bsz * Ssz * Wsz;
  unsigned long long* maskp = (unsigned long long*)(wsf + o); o += Bsz * 2;

  hipMemsetAsync(hA, 0, (size_t)Bsz * Hsz * 4, stream);
  hipMemsetAsync(cE, 0, (size_t)Bsz * Hsz * 4, stream);
  hipMemsetAsync(hdA, 0, (size_t)Bsz * Hsz * 4, stream);
  hipMemsetAsync(maskp, 0, (size_t)Bsz * 8, stream);

  prep_gpack<<<4096, 256, 0, stream>>>(eWhh, WgE);
  prep_gpack<<<4096, 256, 0, stream>>>(dWhh, WgD);
  prep_bpack<<<512, 256, 0, stream>>>(W1, Wb1);
  prep_bpack<<<512, 256, 0, stream>>>(W2, Wb2);
  prep_encin<<<(Vsz * 2048) / 4, 256, 0, stream>>>(emb, eWih, ebih, ebhh, encInP);
  prep_dbias<<<8, 256, 0, stream>>>(dbih, dbhh, dbiasP);

  // host-side: step keys = jax.random.split(jax.random.key(42), 50)
  unsigned kAh[Lsz], kBh[Lsz];
  for (int k = 0; k < Lsz; ++k) {
#if JAX_THREEFRY_PARTITIONABLE
    threefry2x32_hd(0u, 42u, 0u, (unsigned)k, kAh[k], kBh[k]);
#else
    unsigned a0, a1, c0, c1;
    if (k < 25) {
      threefry2x32_hd(0u, 42u, 2u * k,      2u * k + 50u, a0, a1); kAh[k] = a0;
      threefry2x32_hd(0u, 42u, 2u * k + 1u, 2u * k + 51u, c0, c1); kBh[k] = c0;
    } else {
      threefry2x32_hd(0u, 42u, 2u * k - 50u, 2u * k,      a0, a1); kAh[k] = a1;
      threefry2x32_hd(0u, 42u, 2u * k - 49u, 2u * k + 1u, c0, c1); kBh[k] = c1;
    }
#endif
  }

  // encoder
  float* hr = hA; float* hw = hB;
  for (int t = 0; t < Ssz; ++t) {
    gates_step<<<1024, 256, 0, stream>>>(hr, WgE, encInP, input, t, hw, cE);
    blend_gemm<<<512, 256, 0, stream>>>(hw, Wb1, b1 + (size_t)t * Wsz, Ssz * Wsz);
    float* tp = hr; hr = hw; hw = tp;
  }
  // decoder init: c0 = last encoder h (alias, no copy; hr's buffer is dead
  // for the encoder after the loop), h0 = 0 (hdA), mask = 0
  float* cD = hr;

  float* dr = hdA; float* dw = hdB;
  for (int k = 0; k < Lsz; ++k) {
    gates_step<<<1024, 256, 0, stream>>>(dr, WgD, dbiasP, nullptr, 0, dw, cD);
    blend_gemm<<<512, 256, 0, stream>>>(dw, Wb2, b2, Wsz);
    scores_sample<<<Bsz, 256, 0, stream>>>(b1, b2, vt, maskp, outF,
                                           outF + (size_t)Bsz * Lsz * Ssz,
                                           k, kAh[k], kBh[k]);
    float* tp = dr; dr = dw; dw = tp;
  }
}